// Round 11
// baseline (1314.739 us; speedup 1.0000x reference)
//
#include <hip/hip_runtime.h>

// ---------------------------------------------------------------------------
// <psi|U^dag O U|psi>, NQ=8, r=64 d=16 rl=16 ro=4.
// R23 = R22 + g45 LDS aliasing:
//   SL (17.4KB slab/reduce) now ALIASES Bs (32KB B-panel) -- Bs is dead
//   after phase A's MFMAs; one __syncthreads() between phase A and phase B
//   removes the fast-wave/slow-wave hazard. g45 LDS 50176 -> 32768, and
//   fused_g45_g2's shared pool drops to 32768 -> LDS cap 5 blocks/CU for
//   BOTH branches (R22 charged the 50KB pool to g2-branch blocks too,
//   costing g2 its 4-5 blocks/CU: fusedB ran 88.5us vs 79us serial).
// Everything else identical to R22 (bit-identical numerics).
// ---------------------------------------------------------------------------

typedef __attribute__((ext_vector_type(8))) short bf16x8;
typedef __attribute__((ext_vector_type(8))) _Float16 f16x8;
typedef __attribute__((ext_vector_type(4))) float f32x4;
typedef __attribute__((ext_vector_type(4))) unsigned short us4;

static __device__ __forceinline__ unsigned short f2bf(float x) {
    union { float f; unsigned u; } a; a.f = x;
    return (unsigned short)((a.u + 0x7FFF + ((a.u >> 16) & 1)) >> 16);
}
static __device__ __forceinline__ float bf2f(unsigned short h) {
    union { unsigned u; float f; } a; a.u = (unsigned)h << 16; return a.f;
}
static __device__ __forceinline__ unsigned split2(float x) {
    unsigned short h = f2bf(x);
    unsigned short l = f2bf(x - bf2f(h));
    return (unsigned)h | ((unsigned)l << 16);
}
// pair split via HW bf16 cvt (RNE, same bits as f2bf for normals):
static __device__ __forceinline__ void split2_pair(float x0, float x1,
                                                   unsigned& o0, unsigned& o1) {
    unsigned hh, ll;
    asm("v_cvt_pk_bf16_f32 %0, %1, %2" : "=v"(hh) : "v"(x0), "v"(x1));
    union { unsigned u; float f; } c0, c1;
    c0.u = hh << 16;            // bf2f(h0)
    c1.u = hh & 0xffff0000u;    // bf2f(h1)
    float r0 = x0 - c0.f, r1 = x1 - c1.f;
    asm("v_cvt_pk_bf16_f32 %0, %1, %2" : "=v"(ll) : "v"(r0), "v"(r1));
    asm("v_perm_b32 %0, %1, %2, %3" : "=v"(o0) : "v"(ll), "v"(hh), "s"(0x05040100));
    asm("v_perm_b32 %0, %1, %2, %3" : "=v"(o1) : "v"(ll), "v"(hh), "s"(0x07060302));
}
static __device__ __forceinline__ unsigned short f2h_bits(float x) {
    union { _Float16 h; unsigned short u; } c; c.h = (_Float16)x; return c.u;
}
static __device__ __forceinline__ float h2f_bits(unsigned short u) {
    union { unsigned short u; _Float16 h; } c; c.u = u; return (float)c.h;
}
// async global->LDS, 16B per lane; lds base must be wave-uniform.
static __device__ __forceinline__ void gl_lds16(const unsigned short* g,
                                                unsigned short* l) {
    __builtin_amdgcn_global_load_lds(
        (const __attribute__((address_space(1))) unsigned int*)g,
        (__attribute__((address_space(3))) unsigned int*)l, 16, 0, 0);
}

__global__ void write_diag_kernel(float* out, float v) {
    if (threadIdx.x == 0 && blockIdx.x == 0) out[0] = v;
}
__global__ void zero_out(float* o) {
    if (threadIdx.x == 0 && blockIdx.x == 0) o[0] = 0.0f;
}

// ---- A-operand fragment packs -------------------------------------------
__global__ void prep_apack(const float* __restrict__ layer,
                           unsigned short* __restrict__ Ap2,
                           unsigned short* __restrict__ Ap4) {
    int idx = blockIdx.x * 256 + threadIdx.x;   // 65536
    int q = idx >> 13, k0 = (idx >> 10) & 7, mt = (idx >> 6) & 15, lane = idx & 63;
    int quad = lane >> 4, r = lane & 15;
    unsigned short h2[8], l2[8], h4[8], l4[8];
#pragma unroll
    for (int j = 0; j < 8; j++) {
        int k = k0 * 32 + quad * 8 + j;
        int m = mt * 16 + r;
        float v2 = layer[(size_t)q * 65536 +
                         (size_t)((((k >> 4) * 16 + (m >> 4)) * 16 + (k & 15)) * 16 + (m & 15))];
        float v4 = layer[(size_t)q * 65536 +
                         (size_t)((((k >> 4) * 16 + (k & 15)) * 16 + (m >> 4)) * 16 + (m & 15))];
        h2[j] = f2h_bits(v2); l2[j] = f2h_bits(v2 - h2f_bits(h2[j]));
        h4[j] = f2h_bits(v4); l4[j] = f2h_bits(v4 - h2f_bits(h4[j]));
    }
    size_t base = ((size_t)((q * 8 + k0) * 16 + mt) * 2) * 512 + lane * 8;
    *(us4*)(Ap2 + base)       = *(us4*)&h2[0];
    *(us4*)(Ap2 + base + 4)   = *(us4*)&h2[4];
    *(us4*)(Ap2 + base + 512) = *(us4*)&l2[0];
    *(us4*)(Ap2 + base + 516) = *(us4*)&l2[4];
    *(us4*)(Ap4 + base)       = *(us4*)&h4[0];
    *(us4*)(Ap4 + base + 4)   = *(us4*)&h4[4];
    *(us4*)(Ap4 + base + 512) = *(us4*)&l4[0];
    *(us4*)(Ap4 + base + 516) = *(us4*)&l4[4];
}

__global__ void prep_spack1(const float* __restrict__ state,
                            unsigned short* __restrict__ Sp1) {
    int idx = blockIdx.x * 256 + threadIdx.x;   // 65536
    int q = idx >> 13, c = (idx >> 11) & 3, k0 = (idx >> 10) & 1,
        mt = (idx >> 6) & 15, lane = idx & 63;
    int quad = lane >> 4, lr = lane & 15;
    unsigned short h[8], l[8];
#pragma unroll
    for (int j = 0; j < 8; j++) {
        int k = k0 * 32 + quad * 8 + j;
        float v = state[(size_t)q * 65536 + (size_t)(k * 16 + mt) * 64 + c * 16 + lr];
        h[j] = f2bf(v); l[j] = f2bf(v - bf2f(h[j]));
    }
    size_t base = (size_t)(q * 4 + c) * 32768 + ((size_t)(k0 * 16 + mt) * 2) * 512 + lane * 8;
    *(us4*)(Sp1 + base)       = *(us4*)&h[0];
    *(us4*)(Sp1 + base + 4)   = *(us4*)&h[4];
    *(us4*)(Sp1 + base + 512) = *(us4*)&l[0];
    *(us4*)(Sp1 + base + 516) = *(us4*)&l[4];
}

__global__ void prep_spack5(const float* __restrict__ state,
                            unsigned short* __restrict__ Sp5) {
    int idx = blockIdx.x * 256 + threadIdx.x;   // 65536
    int q = idx >> 13, k0 = (idx >> 8) & 31, mt = (idx >> 6) & 3, lane = idx & 63;
    int quad = lane >> 4, lr = lane & 15;
    unsigned short h[8], l[8];
#pragma unroll
    for (int j = 0; j < 8; j++) {
        int k = k0 * 32 + quad * 8 + j;   // k = s*64+b
        int s = k >> 6, b = k & 63;
        float v = state[(size_t)q * 65536 + (size_t)(b * 16 + s) * 64 + mt * 16 + lr];
        h[j] = f2bf(v); l[j] = f2bf(v - bf2f(h[j]));
    }
    size_t base = (size_t)q * 131072 + ((size_t)(k0 * 4 + mt) * 2) * 512 + lane * 8;
    *(us4*)(Sp5 + base)       = *(us4*)&h[0];
    *(us4*)(Sp5 + base + 4)   = *(us4*)&h[4];
    *(us4*)(Sp5 + base + 512) = *(us4*)&l[0];
    *(us4*)(Sp5 + base + 516) = *(us4*)&l[4];
}

__global__ void prep_opack3(const float* __restrict__ oper,
                            unsigned short* __restrict__ Op3) {
    int idx = blockIdx.x * 256 + threadIdx.x;   // 4096
    int q = idx >> 9, k0 = (idx >> 8) & 1, mt = (idx >> 6) & 3, lane = idx & 63;
    int quad = lane >> 4, lr = lane & 15;
    unsigned short h[8], l[8];
#pragma unroll
    for (int j = 0; j < 8; j++) {
        int k = k0 * 32 + quad * 8 + j;
        int m = mt * 16 + lr;
        float v = oper[(size_t)q * 4096 + (size_t)(k * 16 + (m & 15)) * 4 + (m >> 4)];
        h[j] = f2h_bits(v); l[j] = f2h_bits(v - h2f_bits(h[j]));
    }
    size_t base = (size_t)q * 8192 + ((size_t)(k0 * 4 + mt) * 2) * 512 + lane * 8;
    *(us4*)(Op3 + base)       = *(us4*)&h[0];
    *(us4*)(Op3 + base + 4)   = *(us4*)&h[4];
    *(us4*)(Op3 + base + 512) = *(us4*)&l[0];
    *(us4*)(Op3 + base + 516) = *(us4*)&l[4];
}

// ---- env fp32 -> packed u32 (bf16 hi | lo<<16), once after site 0 -------
__global__ void env_split_k(const float* __restrict__ env, unsigned* __restrict__ envS) {
    int t = blockIdx.x * 256 + threadIdx.x;   // 1048576 x float4
    float4 v = ((const float4*)env)[t];
    uint4 o;
    o.x = split2(v.x); o.y = split2(v.y); o.z = split2(v.z); o.w = split2(v.w);
    ((uint4*)envS)[t] = o;
}

// ---- site 0 (env0 = delta): env1 built by a cheap chain (fp32 exact) ----
__global__ void s0_g2(const float* __restrict__ state, const float* __restrict__ layer,
                      float* __restrict__ g2) {
    int t = blockIdx.x * 256 + threadIdx.x;          // 16384: [A][j][L]
    int A = t >> 8, j = (t >> 4) & 15, L = t & 15;
    float s = 0;
    for (int i = 0; i < 16; i++) s += state[i * 64 + A] * layer[(j * 16 + i) * 16 + L];
    g2[t] = s;
}
__global__ void s0_g3(const float* __restrict__ g2, const float* __restrict__ oper,
                      float* __restrict__ g3) {
    int t = blockIdx.x * 256 + threadIdx.x;          // 65536: [A][L][k][O]
    int A = t >> 10, L = (t >> 6) & 15, k = (t >> 2) & 15, O = t & 3;
    float s = 0;
    for (int j = 0; j < 16; j++) s += g2[A * 256 + j * 16 + L] * oper[(j * 16 + k) * 4 + O];
    g3[t] = s;
}
__global__ void s0_g4(const float* __restrict__ g3, const float* __restrict__ layer,
                      float* __restrict__ g4) {
    int t = blockIdx.x * 256 + threadIdx.x;          // 1048576: [A][L][O][s][M]
    int A = t >> 14, L = (t >> 10) & 15, O = (t >> 8) & 3, sp = (t >> 4) & 15, M = t & 15;
    float s = 0;
    for (int k = 0; k < 16; k++)
        s += g3[A * 1024 + L * 64 + k * 4 + O] * layer[(k * 16 + sp) * 16 + M];
    g4[t] = s;
}
__global__ void s0_env(const float* __restrict__ g4, const float* __restrict__ state,
                       float* __restrict__ env) {
    int t = blockIdx.x * 256 + threadIdx.x;          // 4194304
    int A = t >> 16, L = (t >> 12) & 15, O = (t >> 10) & 3, M = (t >> 6) & 15, B = t & 63;
    float s = 0;
    for (int sp = 0; sp < 16; sp++)
        s += g4[A * 16384 + L * 1024 + O * 256 + sp * 16 + M] * state[sp * 64 + B];
    env[(size_t)(L * 64 + O * 16 + M) * 4096 + A * 64 + B] = s;
}

// ---- site 7 chain (fp32) + fused dot ------------------------------------
__global__ void s7_c1(const float* __restrict__ state, const float* __restrict__ layer,
                      float* __restrict__ c1) {
    int t = blockIdx.x * 256 + threadIdx.x;          // 16384: [l][a][j]
    int l = t >> 10, a = (t >> 4) & 63, j = t & 15;
    float s = 0;
    for (int i = 0; i < 16; i++)
        s += state[7 * 65536 + (a * 16 + i) * 64] * layer[7 * 65536 + ((l * 16 + j) * 16 + i) * 16];
    c1[t] = s;
}
__global__ void s7_c2(const float* __restrict__ c1, const float* __restrict__ oper,
                      float* __restrict__ c2) {
    int t = blockIdx.x * 256 + threadIdx.x;          // 65536: [o][l][a][k]
    int o = t >> 14, l = (t >> 10) & 15, a = (t >> 4) & 63, k = t & 15;
    float s = 0;
    for (int j = 0; j < 16; j++)
        s += c1[l * 1024 + a * 16 + j] * oper[7 * 4096 + ((o * 16 + j) * 16 + k) * 4];
    c2[t] = s;
}
__global__ void s7_c3(const float* __restrict__ c2, const float* __restrict__ layer,
                      float* __restrict__ c3) {
    int t = blockIdx.x * 256 + threadIdx.x;          // 1048576: [m][o][l][a][s]
    int m = t >> 16, o = (t >> 14) & 3, l = (t >> 10) & 15, a = (t >> 4) & 63, sp = t & 15;
    float s = 0;
    for (int k = 0; k < 16; k++)
        s += c2[o * 16384 + l * 1024 + a * 16 + k] *
             layer[7 * 65536 + ((m * 16 + k) * 16 + sp) * 16];
    c3[t] = s;
}
__global__ void prep_sv(const float* __restrict__ state, float* __restrict__ sv) {
    int t = blockIdx.x * 256 + threadIdx.x;          // 1024: [b][sp]
    sv[t] = state[7 * 65536 + t * 64];
}
__global__ __launch_bounds__(256) void s7_fused(const float* __restrict__ env,
                                                const float* __restrict__ c3,
                                                const float* __restrict__ sv,
                                                float* __restrict__ out) {
    __shared__ float c3s[1024], svs[1024], red[256];
    int t = threadIdx.x;
    int n0 = blockIdx.x * 64;            // region=(l,o,m)
    int l = n0 >> 12, o = (n0 >> 10) & 3, m = (n0 >> 6) & 15;
    const float* c3b = c3 + m * 65536 + o * 16384 + l * 1024;   // [a][sp]
    const float* eb  = env + (size_t)blockIdx.x * 4096;         // [a][b]
    for (int i = t; i < 1024; i += 256) { c3s[i] = c3b[i]; svs[i] = sv[i]; }
    __syncthreads();
    float s = 0;
    int b = t & 63, ag = t >> 6;
#pragma unroll
    for (int g = 0; g < 16; g++) {
        int a = ag * 16 + g;
        float e = eb[a * 64 + b];
        float w = 0;
#pragma unroll
        for (int sp = 0; sp < 16; sp++) w += c3s[a * 16 + sp] * svs[b * 16 + sp];
        s += e * w;
    }
    red[t] = s; __syncthreads();
    for (int off = 128; off; off >>= 1) { if (t < off) red[t] += red[t + off]; __syncthreads(); }
    if (t == 0) atomicAdd(out, red[0]);
}

// ---- G1 body: envS (pre-split u32, LDS-staged) x Sp1 -> t1 f16 panels ----
// bid in [0,2048): cc = bid>>10, rid = bid & 1023 = [l(16) o(4) m2(16)]
// smem: >= 8320 bytes
static __device__ __forceinline__ void g1_body(int bid, void* smem,
                                               const unsigned* __restrict__ envS,
                                               const unsigned short* __restrict__ Sp1,
                                               unsigned short* __restrict__ t1,
                                               float scale) {
    unsigned* Bt = (unsigned*)smem;
    const int tid = threadIdx.x, lane = tid & 63, wave = tid >> 6;
    const int quad = lane >> 4, lr = lane & 15;
    const int cc = bid >> 10, rid = bid & 1023;
    const int l = rid >> 6, o = (rid >> 4) & 3, m2 = rid & 15;

    f32x4 acc[4][4];
#pragma unroll
    for (int i = 0; i < 4; i++)
#pragma unroll
        for (int j = 0; j < 4; j++)
#pragma unroll
            for (int r = 0; r < 4; r++) acc[i][j][r] = 0.0f;

    const unsigned* Bv = envS + (size_t)rid * 4096;
    const unsigned short* Sp1c = Sp1 + (size_t)cc * 32768;
    uint4 ur[2];
    auto load_tile = [&](int k0) {
        const uint4* src = (const uint4*)(Bv + k0 * 2048);
        ur[0] = src[tid];
        ur[1] = src[256 + tid];
    };
    auto store_tile = [&]() {
#pragma unroll
        for (int v = 0; v < 2; v++) {
            int e = v * 256 + tid;
            unsigned* p = &Bt[(e >> 4) * 65 + (e & 15) * 4];
            p[0] = ur[v].x; p[1] = ur[v].y; p[2] = ur[v].z; p[3] = ur[v].w;
        }
    };

    bf16x8 ahb[2][4], alb[2][4];
    auto loadA = [&](int k0, int buf) {
#pragma unroll
        for (int mt = 0; mt < 4; mt++) {
            int gmt = wave * 4 + mt;
            const unsigned short* ap = Sp1c + ((size_t)(k0 * 16 + gmt) * 2) * 512 + lane * 8;
            ahb[buf][mt] = *(const bf16x8*)ap;
            alb[buf][mt] = *(const bf16x8*)(ap + 512);
        }
    };

    load_tile(0);
    loadA(0, 0);
    store_tile();
#pragma unroll
    for (int k0 = 0; k0 < 2; k0++) {
        __syncthreads();
        if (k0 + 1 < 2) { load_tile(k0 + 1); loadA(k0 + 1, 1); }
#pragma unroll
        for (int nt = 0; nt < 4; nt++) {
            int nl = nt * 16 + lr;
            bf16x8 bh, bl;
#pragma unroll
            for (int j = 0; j < 8; j++) {
                unsigned u = Bt[(quad * 8 + j) * 65 + nl];
                bh[j] = (short)(u & 0xffffu);
                bl[j] = (short)(u >> 16);
            }
#pragma unroll
            for (int mt = 0; mt < 4; mt++) {
                acc[mt][nt] = __builtin_amdgcn_mfma_f32_16x16x32_bf16(ahb[k0][mt], bh, acc[mt][nt], 0, 0, 0);
                acc[mt][nt] = __builtin_amdgcn_mfma_f32_16x16x32_bf16(ahb[k0][mt], bl, acc[mt][nt], 0, 0, 0);
                acc[mt][nt] = __builtin_amdgcn_mfma_f32_16x16x32_bf16(alb[k0][mt], bh, acc[mt][nt], 0, 0, 0);
            }
        }
        __syncthreads();
        if (k0 + 1 < 2) store_tile();
    }

#pragma unroll
    for (int nt = 0; nt < 4; nt++) {
        int b = nt * 16 + lr;
#pragma unroll
        for (int r = 0; r < 4; r++) {
            int a4 = quad * 4 + r;
            us4 w;
#pragma unroll
            for (int mt = 0; mt < 4; mt++) w[mt] = f2h_bits(acc[mt][nt][r] * scale);
            size_t addr = (size_t)cc * 16777216 +
                          (size_t)(o * 256 + m2 * 16 + a4) * 16384 +
                          (size_t)(l * 2 + (wave >> 1)) * 512 + b * 8 + (wave & 1) * 4;
            *(us4*)(t1 + addr) = w;
        }
    }
}

__global__ __launch_bounds__(256) void gemm_g1(const unsigned* __restrict__ envS,
                                               const unsigned short* __restrict__ Sp1,
                                               unsigned short* __restrict__ t1,
                                               float scale) {
    __shared__ unsigned Bt[32 * 65];
    g1_body(blockIdx.x, Bt, envS, Sp1, t1, scale);
}

// ---- G2 body: B panel LDS-staged via global_load_lds; A depth-2 prefetch -
// bid in [0,2048): cc = bid>>10, rid = [o(4) m2(16) a4(16)]
// smem: >= 32768 bytes, 16-aligned
static __device__ __forceinline__ void g2_body(int bid, void* smem,
                                               const unsigned short* __restrict__ Bp,
                                               const unsigned short* __restrict__ Ap,
                                               unsigned short* __restrict__ Co) {
    unsigned short* Bs = (unsigned short*)smem;
    const int tid = threadIdx.x, lane = tid & 63, wave = tid >> 6;
    const int quad = lane >> 4, lr = lane & 15;
    const int cc = bid >> 10, rid = bid & 1023;
    const int o = rid >> 8, m2 = (rid >> 4) & 15, a4 = rid & 15;
    const unsigned short* pb = Bp + (size_t)bid * 16384;
    unsigned short* Cb = Co + (size_t)cc * 16777216;

#pragma unroll
    for (int i = 0; i < 8; i++)
        gl_lds16(pb + i * 2048 + tid * 8, Bs + i * 2048 + wave * 512);

    f32x4 acc[4][4];
#pragma unroll
    for (int i = 0; i < 4; i++)
#pragma unroll
        for (int j = 0; j < 4; j++)
#pragma unroll
            for (int r = 0; r < 4; r++) acc[i][j][r] = 0.0f;

    f16x8 ah[3][4];
    auto loadA = [&](int k0, int buf) {
#pragma unroll
        for (int mt = 0; mt < 4; mt++) {
            int gmt = wave * 4 + mt;
            ah[buf][mt] = *(const f16x8*)(Ap + ((size_t)(k0 * 16 + gmt) * 2) * 512 + lane * 8);
        }
    };
    loadA(0, 0);
    loadA(1, 1);

    asm volatile("s_waitcnt vmcnt(0)" ::: "memory");
    __syncthreads();

#pragma unroll
    for (int k0 = 0; k0 < 8; k0++) {
        if (k0 + 2 < 8) loadA(k0 + 2, (k0 + 2) % 3);
        f16x8 bfr[4];
#pragma unroll
        for (int nt = 0; nt < 4; nt++)
            bfr[nt] = *(const f16x8*)(Bs + (k0 * 4 + quad) * 512 + (nt * 16 + lr) * 8);
#pragma unroll
        for (int nt = 0; nt < 4; nt++)
#pragma unroll
            for (int mt = 0; mt < 4; mt++)
                acc[mt][nt] = __builtin_amdgcn_mfma_f32_16x16x32_f16(
                    ah[k0 % 3][mt], bfr[nt], acc[mt][nt], 0, 0, 0);
    }

#pragma unroll
    for (int nt = 0; nt < 4; nt++) {
        int b = nt * 16 + lr;
#pragma unroll
        for (int r = 0; r < 4; r++) {
            int L = quad * 4 + r;
            us4 w;
#pragma unroll
            for (int mt = 0; mt < 4; mt++) w[mt] = f2h_bits(acc[mt][nt][r]);
            size_t addr = (size_t)(L * 256 + m2 * 16 + a4) * 4096 +
                          (size_t)(o * 2 + (wave >> 1)) * 512 + b * 8 + (wave & 1) * 4;
            *(us4*)(Cb + addr) = w;
        }
    }
}

// ---- G45 body: fused G3+G4+G5 --------------------------------------------
// bid in [0,2048): cc = bid>>10; rid = g*32 + O2*8 + low, panel=(L,a4)=g*8+low
// smem: >= 32768 bytes (SL 17408 ALIASES Bs 32768 -- Bs dead after phase A;
// a __syncthreads() separates phase A reads from phase B slab writes).
static __device__ __forceinline__ void g45_body(int bid, void* smem,
                                                const unsigned short* __restrict__ T2,
                                                const unsigned short* __restrict__ Op3q,
                                                const unsigned short* __restrict__ Ap4,
                                                const unsigned short* __restrict__ Sp5,
                                                float* __restrict__ env,
                                                unsigned* __restrict__ envSo,
                                                int A0, float inv, int wf32) {
    unsigned short* Bs = (unsigned short*)smem;              // 32768 B
    unsigned* SL = (unsigned*)smem;                          // aliases Bs
    const int tid = threadIdx.x, lane = tid & 63, wave = tid >> 6;
    const int quad = lane >> 4, lr = lane & 15;
    const int cc = bid >> 10, rid = bid & 1023;
    const int low = rid & 7, O2 = (rid >> 3) & 3, g = rid >> 5;
    const int panel = g * 8 + low;           // = L*16 + a4
    const int L = panel >> 4, a4 = panel & 15;
    const unsigned short* T2c = T2 + (size_t)cc * 16777216;
    const int b8 = (wave * 16 + lr) * 8;   // b*8, b = wave*16+lr (g3 layout)

    // phase-A A-panel prefetch rides alongside the prologue
    f16x8 ah[3][4];
    auto loadA = [&](int k0, int buf) {
#pragma unroll
        for (int mt = 0; mt < 4; mt++) {
            int gmt = wave * 4 + mt;
            ah[buf][mt] = *(const f16x8*)(Ap4 + ((size_t)(k0 * 16 + gmt) * 2) * 512 + lane * 8);
        }
    };
    loadA(0, 0);
    loadA(1, 1);

    // ---- fused G3 prologue: build Bs = Op3[O2] x T2[(L,m2,a4)] -----------
    {
        f16x8 oh0 = *(const f16x8*)(Op3q + (size_t)(O2 * 2) * 512 + lane * 8);
        f16x8 oh1 = *(const f16x8*)(Op3q + (size_t)((4 + O2) * 2) * 512 + lane * 8);
        f16x8 tb[5][2];    // depth-4 ring
        auto loadT2 = [&](int m2, int buf) {
            const unsigned short* pp = T2c + (size_t)(L * 256 + m2 * 16 + a4) * 4096;
            tb[buf][0] = *(const f16x8*)(pp + (quad << 9) + b8);
            tb[buf][1] = *(const f16x8*)(pp + ((4 + quad) << 9) + b8);
        };
        loadT2(0, 0); loadT2(1, 1); loadT2(2, 2); loadT2(3, 3);
#pragma unroll
        for (int m2 = 0; m2 < 16; m2++) {
            if (m2 + 4 < 16) loadT2(m2 + 4, (m2 + 4) % 5);
            f32x4 a3;
            a3[0] = a3[1] = a3[2] = a3[3] = 0.0f;
            a3 = __builtin_amdgcn_mfma_f32_16x16x32_f16(oh0, tb[m2 % 5][0], a3, 0, 0, 0);
            a3 = __builtin_amdgcn_mfma_f32_16x16x32_f16(oh1, tb[m2 % 5][1], a3, 0, 0, 0);
            us4 w;
#pragma unroll
            for (int r = 0; r < 4; r++) w[r] = f2h_bits(a3[r]);
            *(us4*)(Bs + (m2 * 2 + (quad >> 1)) * 512 + b8 + (quad & 1) * 4) = w;
        }
    }
    __syncthreads();

    f32x4 acc[4][4];
#pragma unroll
    for (int i = 0; i < 4; i++)
#pragma unroll
        for (int j = 0; j < 4; j++)
#pragma unroll
            for (int r = 0; r < 4; r++) acc[i][j][r] = 0.0f;

#pragma unroll
    for (int k0 = 0; k0 < 8; k0++) {
        if (k0 + 2 < 8) loadA(k0 + 2, (k0 + 2) % 3);
        f16x8 bfr[4];
#pragma unroll
        for (int nt = 0; nt < 4; nt++)
            bfr[nt] = *(const f16x8*)(Bs + (k0 * 4 + quad) * 512 + (nt * 16 + lr) * 8);
#pragma unroll
        for (int nt = 0; nt < 4; nt++)
#pragma unroll
            for (int mt = 0; mt < 4; mt++)
                acc[mt][nt] = __builtin_amdgcn_mfma_f32_16x16x32_f16(
                    ah[k0 % 3][mt], bfr[nt], acc[mt][nt], 0, 0, 0);
    }

    // all waves done reading Bs before slab writes alias it
    __syncthreads();

    // phase B: per-wave k-quarter (s = 4*wave..4*wave+3), barrier-free.
    unsigned* myslab = SL + wave * (16 * 68);
    f32x4 acc5[4];
#pragma unroll
    for (int nt = 0; nt < 4; nt++)
#pragma unroll
        for (int r = 0; r < 4; r++) acc5[nt][r] = 0.0f;

    // Sp5 depth-1 pipeline: step = mtp*2+h, buffers by step parity.
    bf16x8 s5h[2][4], s5l[2][4];
    auto loadS5 = [&](int step, int buf) {
        int kg = (wave * 4 + (step >> 1)) * 2 + (step & 1);
#pragma unroll
        for (int nt = 0; nt < 4; nt++) {
            const unsigned short* bp = Sp5 + ((size_t)(kg * 4 + nt) * 2) * 512 + lane * 8;
            s5h[buf][nt] = *(const bf16x8*)bp;
            s5l[buf][nt] = *(const bf16x8*)(bp + 512);
        }
    };
    loadS5(0, 0);

#pragma unroll
    for (int mtp = 0; mtp < 4; mtp++) {
        // deposit own slab [M2=16][b=64 pad 68] via HW cvt_pk pairs
#pragma unroll
        for (int nt = 0; nt < 4; nt++) {
            unsigned o0, o1, o2, o3;
            split2_pair(acc[mtp][nt][0], acc[mtp][nt][1], o0, o1);
            split2_pair(acc[mtp][nt][2], acc[mtp][nt][3], o2, o3);
            myslab[(quad * 4 + 0) * 68 + nt * 16 + lr] = o0;
            myslab[(quad * 4 + 1) * 68 + nt * 16 + lr] = o1;
            myslab[(quad * 4 + 2) * 68 + nt * 16 + lr] = o2;
            myslab[(quad * 4 + 3) * 68 + nt * 16 + lr] = o3;
        }
        // same-wave cross-lane LDS dependency: drain LDS pipe (vmcnt loads
        // from loadS5 stay in flight - lgkmcnt does not wait on them)
        asm volatile("s_waitcnt lgkmcnt(0)" ::: "memory");
#pragma unroll
        for (int h = 0; h < 2; h++) {
            const int step = mtp * 2 + h;
            const unsigned* sp = &myslab[lr * 68 + h * 32 + quad * 8];
            uint4 u0 = *(const uint4*)sp;
            uint4 u1 = *(const uint4*)(sp + 4);
            bf16x8 th, tl;
            th[0] = (short)(u0.x & 0xffff); tl[0] = (short)(u0.x >> 16);
            th[1] = (short)(u0.y & 0xffff); tl[1] = (short)(u0.y >> 16);
            th[2] = (short)(u0.z & 0xffff); tl[2] = (short)(u0.z >> 16);
            th[3] = (short)(u0.w & 0xffff); tl[3] = (short)(u0.w >> 16);
            th[4] = (short)(u1.x & 0xffff); tl[4] = (short)(u1.x >> 16);
            th[5] = (short)(u1.y & 0xffff); tl[5] = (short)(u1.y >> 16);
            th[6] = (short)(u1.z & 0xffff); tl[6] = (short)(u1.z >> 16);
            th[7] = (short)(u1.w & 0xffff); tl[7] = (short)(u1.w >> 16);
            if (step + 1 < 8) loadS5(step + 1, (step + 1) & 1);
#pragma unroll
            for (int nt = 0; nt < 4; nt++) {
                acc5[nt] = __builtin_amdgcn_mfma_f32_16x16x32_bf16(th, s5h[step & 1][nt], acc5[nt], 0, 0, 0);
                acc5[nt] = __builtin_amdgcn_mfma_f32_16x16x32_bf16(th, s5l[step & 1][nt], acc5[nt], 0, 0, 0);
                acc5[nt] = __builtin_amdgcn_mfma_f32_16x16x32_bf16(tl, s5h[step & 1][nt], acc5[nt], 0, 0, 0);
            }
        }
    }

    // cross-wave reduce: one barrier, float view of SL
    __syncthreads();
    float* red = (float*)SL;
#pragma unroll
    for (int nt = 0; nt < 4; nt++)
#pragma unroll
        for (int r = 0; r < 4; r++)
            red[wave * 1088 + (quad * 4 + r) * 68 + nt * 16 + lr] = acc5[nt][r];
    __syncthreads();
    float wv[4];
#pragma unroll
    for (int r = 0; r < 4; r++) {
        int M2 = quad * 4 + r, Bc = wave * 16 + lr;
        float v = red[M2 * 68 + Bc] + red[1088 + M2 * 68 + Bc] +
                  red[2176 + M2 * 68 + Bc] + red[3264 + M2 * 68 + Bc];
        wv[r] = v * inv;
    }
    unsigned s0p, s1p, s2p, s3p;
    split2_pair(wv[0], wv[1], s0p, s1p);
    split2_pair(wv[2], wv[3], s2p, s3p);
    unsigned sp4[4] = {s0p, s1p, s2p, s3p};
#pragma unroll
    for (int r = 0; r < 4; r++) {
        int M2 = quad * 4 + r, Bc = wave * 16 + lr;
        size_t idx = (size_t)(L * 64 + O2 * 16 + M2) * 4096 + (A0 + cc * 16 + a4) * 64 + Bc;
        envSo[idx] = sp4[r];
        if (wf32) env[idx] = wv[r];
    }
}

__global__ __launch_bounds__(256) void gemm_g45(const unsigned short* __restrict__ T2,
                                                const unsigned short* __restrict__ Op3q,
                                                const unsigned short* __restrict__ Ap4,
                                                const unsigned short* __restrict__ Sp5,
                                                float* __restrict__ env,
                                                unsigned* __restrict__ envSo,
                                                int A0, float inv, int wf32) {
    __shared__ __align__(16) unsigned char smem[32768];
    g45_body(blockIdx.x, smem, T2, Op3q, Ap4, Sp5, env, envSo, A0, inv, wf32);
}

// ---- fused heterogeneous A: g2(p0) || g1(p1), 8-granular interleave ------
// grp = bid>>3 alternates branches; sub = (grp>>1)*8 + (bid&7).
// Both branches span all 8 XCDs; pool = max(32KB, 8.3KB) = 32KB.
__global__ __launch_bounds__(256) void fused_g2_g1(
        const unsigned short* __restrict__ Bp,     // g2: T1p0
        const unsigned short* __restrict__ Ap,     // g2: Ap2
        unsigned short* __restrict__ Co,           // g2: T2p0
        const unsigned* __restrict__ envS,         // g1: einS
        const unsigned short* __restrict__ Sp1b,   // g1: Sp1 p1 slice
        unsigned short* __restrict__ t1,           // g1: T1p1
        float scale) {
    __shared__ __align__(16) unsigned char smem[32768];
    const int grp = blockIdx.x >> 3;
    const int sub = (grp >> 1) * 8 + (blockIdx.x & 7);
    if (grp & 1)
        g1_body(sub, smem, envS, Sp1b, t1, scale);
    else
        g2_body(sub, smem, Bp, Ap, Co);
}

// ---- fused heterogeneous B: g45(p0) || g2(p1), 8-granular interleave -----
// pool = max(32768, 32768) = 32768 (g45's SL aliases its Bs).
__global__ __launch_bounds__(256) void fused_g45_g2(
        const unsigned short* __restrict__ T2a,    // g45: T2p0
        const unsigned short* __restrict__ Op3q,
        const unsigned short* __restrict__ Ap4,
        const unsigned short* __restrict__ Sp5,
        float* __restrict__ env, unsigned* __restrict__ envSo,
        float inv, int wf32,
        const unsigned short* __restrict__ Bp,     // g2: T1p1
        const unsigned short* __restrict__ Ap,     // g2: Ap2
        unsigned short* __restrict__ Co) {         // g2: T2p1
    __shared__ __align__(16) unsigned char smem[32768];
    const int grp = blockIdx.x >> 3;
    const int sub = (grp >> 1) * 8 + (blockIdx.x & 7);
    if (grp & 1)
        g2_body(sub, smem, Bp, Ap, Co);
    else
        g45_body(sub, smem, T2a, Op3q, Ap4, Sp5, env, envSo, 0, inv, wf32);
}

extern "C" void kernel_launch(void* const* d_in, const int* in_sizes, int n_in,
                              void* d_out, int out_size, void* d_ws, size_t ws_size,
                              hipStream_t stream) {
    const float* state = (const float*)d_in[0];   // [8,64,16,64]
    const float* layer = (const float*)d_in[1];   // [1,8,16,16,16,16]
    const float* oper  = (const float*)d_in[2];   // [8,4,16,16,4]
    float* out = (float*)d_out;

    // F 64MiB (T2p0/SCR) | P 128MiB (T1p0|T2p1 + T1p1) | envS0 | envB | envS1
    const size_t need = 16777216ull * 4 + 33554432ull * 4 + 3ull * 4194304ull * 4 +
                        (4ull * 1048576ull + 65536ull) * 2ull + 4096ull;
    if (ws_size < need) {
        write_diag_kernel<<<1, 64, 0, stream>>>(out, (float)ws_size);
        return;
    }
    float* F    = (float*)d_ws;                          // SCR fp32 / T2p0 u16
    unsigned* P = (unsigned*)(F + 16777216);             // T1p0(|T2p1) + T1p1
    unsigned* envS0 = (unsigned*)(P + 33554432);
    float* envB = (float*)(envS0 + 4194304);
    unsigned* envS1 = (unsigned*)(envB + 4194304);
    unsigned short* Ap2 = (unsigned short*)(envS1 + 4194304);
    unsigned short* Ap4 = Ap2 + 1048576;
    unsigned short* Sp1 = Ap4 + 1048576;
    unsigned short* Sp5 = Sp1 + 1048576;
    unsigned short* Op3 = Sp5 + 1048576;
    float* sv = (float*)(Op3 + 65536);
    float* SCR = F;
    unsigned short* T1p0 = (unsigned short*)P;           // aliased by T2p1
    unsigned short* T1p1 = T1p0 + 33554432;
    unsigned short* T2p0 = (unsigned short*)F;
    unsigned short* T2p1 = T1p0;                         // T1p0 dead by then

    prep_apack<<<256, 256, 0, stream>>>(layer, Ap2, Ap4);
    prep_spack1<<<256, 256, 0, stream>>>(state, Sp1);
    prep_spack5<<<256, 256, 0, stream>>>(state, Sp5);
    prep_opack3<<<16, 256, 0, stream>>>(oper, Op3);
    prep_sv<<<4, 256, 0, stream>>>(state, sv);

    // site 0 -> envB (exact fp32), then one split into envS1
    s0_g2<<<64, 256, 0, stream>>>(state, layer, SCR);
    s0_g3<<<256, 256, 0, stream>>>(SCR, oper, SCR + 16384);
    s0_g4<<<4096, 256, 0, stream>>>(SCR + 16384, layer, SCR + 81920);
    s0_env<<<16384, 256, 0, stream>>>(SCR + 81920, state, envB);
    env_split_k<<<4096, 256, 0, stream>>>(envB, envS1);

    for (int q = 1; q < 7; q++) {
        unsigned* einS  = (q & 1) ? envS1 : envS0;
        unsigned* eoutS = (q & 1) ? envS0 : envS1;
        float scl = (float)(1u << (16 + 2 * q));   // exact power of 2
        float inv = 1.0f / scl;
        int wf32 = (q == 6) ? 1 : 0;
        // g1(p0): einS -> T1p0
        gemm_g1<<<2048, 256, 0, stream>>>(
            einS, Sp1 + (size_t)(q * 4 + 0) * 32768, T1p0, scl);
        // fused A: g2(p0): T1p0 -> T2p0  ||  g1(p1): einS -> T1p1
        fused_g2_g1<<<4096, 256, 0, stream>>>(
            T1p0, Ap2 + (size_t)q * 131072, T2p0,
            einS, Sp1 + (size_t)(q * 4 + 2) * 32768, T1p1, scl);
        // fused B: g45(p0): T2p0 -> eoutS[A 0..31]  ||  g2(p1): T1p1 -> T2p1
        fused_g45_g2<<<4096, 256, 0, stream>>>(
            T2p0, Op3 + (size_t)q * 8192, Ap4 + (size_t)q * 131072,
            Sp5 + (size_t)q * 131072, envB, eoutS, inv, wf32,
            T1p1, Ap2 + (size_t)q * 131072, T2p1);
        // g45(p1): T2p1 -> eoutS[A 32..63]
        gemm_g45<<<2048, 256, 0, stream>>>(
            T2p1, Op3 + (size_t)q * 8192, Ap4 + (size_t)q * 131072,
            Sp5 + (size_t)q * 131072, envB, eoutS, 32, inv, wf32);
    }

    // site 7: out = <env7 (in envB), w>
    s7_c1<<<64, 256, 0, stream>>>(state, layer, SCR);
    s7_c2<<<256, 256, 0, stream>>>(SCR, oper, SCR + 16384);
    s7_c3<<<4096, 256, 0, stream>>>(SCR + 16384, layer, SCR + 81920);
    zero_out<<<1, 64, 0, stream>>>(out);
    s7_fused<<<1024, 256, 0, stream>>>(envB, SCR + 81920, sv, out);
}

// Round 12
// 1283.155 us; speedup vs baseline: 1.0246x; 1.0246x over previous
//
#include <hip/hip_runtime.h>

// ---------------------------------------------------------------------------
// <psi|U^dag O U|psi>, NQ=8, r=64 d=16 rl=16 ro=4.
// R24 = R23 with fusion B REVERTED to serial (g45(p0); g2(p1)):
//   measured fusedB = 88.8us vs 79-83us serial equivalent -- the g2 branch
//   halves g45's temporal T2-panel adjacency and evicts T2p0 from L2, and
//   since BOTH branches are VGPR-capped (not LDS-capped: R23 proved 50K->32K
//   LDS moved nothing), co-residency cannot raise total waves. Fusion A
//   (g2||g1, balanced, 32KB-max pool, 8-granular) stays -- it was the win.
//   Keeps: LDS-aliased g45 (32KB), T2p1 aliasing T1p0, 8-granular fusedA.
// Per q: g1(p0); [g2(p0)||g1(p1)]; g45(p0); g2(p1); g45(p1).
// Bit-identical numerics throughout.
// ---------------------------------------------------------------------------

typedef __attribute__((ext_vector_type(8))) short bf16x8;
typedef __attribute__((ext_vector_type(8))) _Float16 f16x8;
typedef __attribute__((ext_vector_type(4))) float f32x4;
typedef __attribute__((ext_vector_type(4))) unsigned short us4;

static __device__ __forceinline__ unsigned short f2bf(float x) {
    union { float f; unsigned u; } a; a.f = x;
    return (unsigned short)((a.u + 0x7FFF + ((a.u >> 16) & 1)) >> 16);
}
static __device__ __forceinline__ float bf2f(unsigned short h) {
    union { unsigned u; float f; } a; a.u = (unsigned)h << 16; return a.f;
}
static __device__ __forceinline__ unsigned split2(float x) {
    unsigned short h = f2bf(x);
    unsigned short l = f2bf(x - bf2f(h));
    return (unsigned)h | ((unsigned)l << 16);
}
// pair split via HW bf16 cvt (RNE, same bits as f2bf for normals):
static __device__ __forceinline__ void split2_pair(float x0, float x1,
                                                   unsigned& o0, unsigned& o1) {
    unsigned hh, ll;
    asm("v_cvt_pk_bf16_f32 %0, %1, %2" : "=v"(hh) : "v"(x0), "v"(x1));
    union { unsigned u; float f; } c0, c1;
    c0.u = hh << 16;            // bf2f(h0)
    c1.u = hh & 0xffff0000u;    // bf2f(h1)
    float r0 = x0 - c0.f, r1 = x1 - c1.f;
    asm("v_cvt_pk_bf16_f32 %0, %1, %2" : "=v"(ll) : "v"(r0), "v"(r1));
    asm("v_perm_b32 %0, %1, %2, %3" : "=v"(o0) : "v"(ll), "v"(hh), "s"(0x05040100));
    asm("v_perm_b32 %0, %1, %2, %3" : "=v"(o1) : "v"(ll), "v"(hh), "s"(0x07060302));
}
static __device__ __forceinline__ unsigned short f2h_bits(float x) {
    union { _Float16 h; unsigned short u; } c; c.h = (_Float16)x; return c.u;
}
static __device__ __forceinline__ float h2f_bits(unsigned short u) {
    union { unsigned short u; _Float16 h; } c; c.u = u; return (float)c.h;
}
// async global->LDS, 16B per lane; lds base must be wave-uniform.
static __device__ __forceinline__ void gl_lds16(const unsigned short* g,
                                                unsigned short* l) {
    __builtin_amdgcn_global_load_lds(
        (const __attribute__((address_space(1))) unsigned int*)g,
        (__attribute__((address_space(3))) unsigned int*)l, 16, 0, 0);
}

__global__ void write_diag_kernel(float* out, float v) {
    if (threadIdx.x == 0 && blockIdx.x == 0) out[0] = v;
}
__global__ void zero_out(float* o) {
    if (threadIdx.x == 0 && blockIdx.x == 0) o[0] = 0.0f;
}

// ---- A-operand fragment packs -------------------------------------------
__global__ void prep_apack(const float* __restrict__ layer,
                           unsigned short* __restrict__ Ap2,
                           unsigned short* __restrict__ Ap4) {
    int idx = blockIdx.x * 256 + threadIdx.x;   // 65536
    int q = idx >> 13, k0 = (idx >> 10) & 7, mt = (idx >> 6) & 15, lane = idx & 63;
    int quad = lane >> 4, r = lane & 15;
    unsigned short h2[8], l2[8], h4[8], l4[8];
#pragma unroll
    for (int j = 0; j < 8; j++) {
        int k = k0 * 32 + quad * 8 + j;
        int m = mt * 16 + r;
        float v2 = layer[(size_t)q * 65536 +
                         (size_t)((((k >> 4) * 16 + (m >> 4)) * 16 + (k & 15)) * 16 + (m & 15))];
        float v4 = layer[(size_t)q * 65536 +
                         (size_t)((((k >> 4) * 16 + (k & 15)) * 16 + (m >> 4)) * 16 + (m & 15))];
        h2[j] = f2h_bits(v2); l2[j] = f2h_bits(v2 - h2f_bits(h2[j]));
        h4[j] = f2h_bits(v4); l4[j] = f2h_bits(v4 - h2f_bits(h4[j]));
    }
    size_t base = ((size_t)((q * 8 + k0) * 16 + mt) * 2) * 512 + lane * 8;
    *(us4*)(Ap2 + base)       = *(us4*)&h2[0];
    *(us4*)(Ap2 + base + 4)   = *(us4*)&h2[4];
    *(us4*)(Ap2 + base + 512) = *(us4*)&l2[0];
    *(us4*)(Ap2 + base + 516) = *(us4*)&l2[4];
    *(us4*)(Ap4 + base)       = *(us4*)&h4[0];
    *(us4*)(Ap4 + base + 4)   = *(us4*)&h4[4];
    *(us4*)(Ap4 + base + 512) = *(us4*)&l4[0];
    *(us4*)(Ap4 + base + 516) = *(us4*)&l4[4];
}

__global__ void prep_spack1(const float* __restrict__ state,
                            unsigned short* __restrict__ Sp1) {
    int idx = blockIdx.x * 256 + threadIdx.x;   // 65536
    int q = idx >> 13, c = (idx >> 11) & 3, k0 = (idx >> 10) & 1,
        mt = (idx >> 6) & 15, lane = idx & 63;
    int quad = lane >> 4, lr = lane & 15;
    unsigned short h[8], l[8];
#pragma unroll
    for (int j = 0; j < 8; j++) {
        int k = k0 * 32 + quad * 8 + j;
        float v = state[(size_t)q * 65536 + (size_t)(k * 16 + mt) * 64 + c * 16 + lr];
        h[j] = f2bf(v); l[j] = f2bf(v - bf2f(h[j]));
    }
    size_t base = (size_t)(q * 4 + c) * 32768 + ((size_t)(k0 * 16 + mt) * 2) * 512 + lane * 8;
    *(us4*)(Sp1 + base)       = *(us4*)&h[0];
    *(us4*)(Sp1 + base + 4)   = *(us4*)&h[4];
    *(us4*)(Sp1 + base + 512) = *(us4*)&l[0];
    *(us4*)(Sp1 + base + 516) = *(us4*)&l[4];
}

__global__ void prep_spack5(const float* __restrict__ state,
                            unsigned short* __restrict__ Sp5) {
    int idx = blockIdx.x * 256 + threadIdx.x;   // 65536
    int q = idx >> 13, k0 = (idx >> 8) & 31, mt = (idx >> 6) & 3, lane = idx & 63;
    int quad = lane >> 4, lr = lane & 15;
    unsigned short h[8], l[8];
#pragma unroll
    for (int j = 0; j < 8; j++) {
        int k = k0 * 32 + quad * 8 + j;   // k = s*64+b
        int s = k >> 6, b = k & 63;
        float v = state[(size_t)q * 65536 + (size_t)(b * 16 + s) * 64 + mt * 16 + lr];
        h[j] = f2bf(v); l[j] = f2bf(v - bf2f(h[j]));
    }
    size_t base = (size_t)q * 131072 + ((size_t)(k0 * 4 + mt) * 2) * 512 + lane * 8;
    *(us4*)(Sp5 + base)       = *(us4*)&h[0];
    *(us4*)(Sp5 + base + 4)   = *(us4*)&h[4];
    *(us4*)(Sp5 + base + 512) = *(us4*)&l[0];
    *(us4*)(Sp5 + base + 516) = *(us4*)&l[4];
}

__global__ void prep_opack3(const float* __restrict__ oper,
                            unsigned short* __restrict__ Op3) {
    int idx = blockIdx.x * 256 + threadIdx.x;   // 4096
    int q = idx >> 9, k0 = (idx >> 8) & 1, mt = (idx >> 6) & 3, lane = idx & 63;
    int quad = lane >> 4, lr = lane & 15;
    unsigned short h[8], l[8];
#pragma unroll
    for (int j = 0; j < 8; j++) {
        int k = k0 * 32 + quad * 8 + j;
        int m = mt * 16 + lr;
        float v = oper[(size_t)q * 4096 + (size_t)(k * 16 + (m & 15)) * 4 + (m >> 4)];
        h[j] = f2h_bits(v); l[j] = f2h_bits(v - h2f_bits(h[j]));
    }
    size_t base = (size_t)q * 8192 + ((size_t)(k0 * 4 + mt) * 2) * 512 + lane * 8;
    *(us4*)(Op3 + base)       = *(us4*)&h[0];
    *(us4*)(Op3 + base + 4)   = *(us4*)&h[4];
    *(us4*)(Op3 + base + 512) = *(us4*)&l[0];
    *(us4*)(Op3 + base + 516) = *(us4*)&l[4];
}

// ---- env fp32 -> packed u32 (bf16 hi | lo<<16), once after site 0 -------
__global__ void env_split_k(const float* __restrict__ env, unsigned* __restrict__ envS) {
    int t = blockIdx.x * 256 + threadIdx.x;   // 1048576 x float4
    float4 v = ((const float4*)env)[t];
    uint4 o;
    o.x = split2(v.x); o.y = split2(v.y); o.z = split2(v.z); o.w = split2(v.w);
    ((uint4*)envS)[t] = o;
}

// ---- site 0 (env0 = delta): env1 built by a cheap chain (fp32 exact) ----
__global__ void s0_g2(const float* __restrict__ state, const float* __restrict__ layer,
                      float* __restrict__ g2) {
    int t = blockIdx.x * 256 + threadIdx.x;          // 16384: [A][j][L]
    int A = t >> 8, j = (t >> 4) & 15, L = t & 15;
    float s = 0;
    for (int i = 0; i < 16; i++) s += state[i * 64 + A] * layer[(j * 16 + i) * 16 + L];
    g2[t] = s;
}
__global__ void s0_g3(const float* __restrict__ g2, const float* __restrict__ oper,
                      float* __restrict__ g3) {
    int t = blockIdx.x * 256 + threadIdx.x;          // 65536: [A][L][k][O]
    int A = t >> 10, L = (t >> 6) & 15, k = (t >> 2) & 15, O = t & 3;
    float s = 0;
    for (int j = 0; j < 16; j++) s += g2[A * 256 + j * 16 + L] * oper[(j * 16 + k) * 4 + O];
    g3[t] = s;
}
__global__ void s0_g4(const float* __restrict__ g3, const float* __restrict__ layer,
                      float* __restrict__ g4) {
    int t = blockIdx.x * 256 + threadIdx.x;          // 1048576: [A][L][O][s][M]
    int A = t >> 14, L = (t >> 10) & 15, O = (t >> 8) & 3, sp = (t >> 4) & 15, M = t & 15;
    float s = 0;
    for (int k = 0; k < 16; k++)
        s += g3[A * 1024 + L * 64 + k * 4 + O] * layer[(k * 16 + sp) * 16 + M];
    g4[t] = s;
}
__global__ void s0_env(const float* __restrict__ g4, const float* __restrict__ state,
                       float* __restrict__ env) {
    int t = blockIdx.x * 256 + threadIdx.x;          // 4194304
    int A = t >> 16, L = (t >> 12) & 15, O = (t >> 10) & 3, M = (t >> 6) & 15, B = t & 63;
    float s = 0;
    for (int sp = 0; sp < 16; sp++)
        s += g4[A * 16384 + L * 1024 + O * 256 + sp * 16 + M] * state[sp * 64 + B];
    env[(size_t)(L * 64 + O * 16 + M) * 4096 + A * 64 + B] = s;
}

// ---- site 7 chain (fp32) + fused dot ------------------------------------
__global__ void s7_c1(const float* __restrict__ state, const float* __restrict__ layer,
                      float* __restrict__ c1) {
    int t = blockIdx.x * 256 + threadIdx.x;          // 16384: [l][a][j]
    int l = t >> 10, a = (t >> 4) & 63, j = t & 15;
    float s = 0;
    for (int i = 0; i < 16; i++)
        s += state[7 * 65536 + (a * 16 + i) * 64] * layer[7 * 65536 + ((l * 16 + j) * 16 + i) * 16];
    c1[t] = s;
}
__global__ void s7_c2(const float* __restrict__ c1, const float* __restrict__ oper,
                      float* __restrict__ c2) {
    int t = blockIdx.x * 256 + threadIdx.x;          // 65536: [o][l][a][k]
    int o = t >> 14, l = (t >> 10) & 15, a = (t >> 4) & 63, k = t & 15;
    float s = 0;
    for (int j = 0; j < 16; j++)
        s += c1[l * 1024 + a * 16 + j] * oper[7 * 4096 + ((o * 16 + j) * 16 + k) * 4];
    c2[t] = s;
}
__global__ void s7_c3(const float* __restrict__ c2, const float* __restrict__ layer,
                      float* __restrict__ c3) {
    int t = blockIdx.x * 256 + threadIdx.x;          // 1048576: [m][o][l][a][s]
    int m = t >> 16, o = (t >> 14) & 3, l = (t >> 10) & 15, a = (t >> 4) & 63, sp = t & 15;
    float s = 0;
    for (int k = 0; k < 16; k++)
        s += c2[o * 16384 + l * 1024 + a * 16 + k] *
             layer[7 * 65536 + ((m * 16 + k) * 16 + sp) * 16];
    c3[t] = s;
}
__global__ void prep_sv(const float* __restrict__ state, float* __restrict__ sv) {
    int t = blockIdx.x * 256 + threadIdx.x;          // 1024: [b][sp]
    sv[t] = state[7 * 65536 + t * 64];
}
__global__ __launch_bounds__(256) void s7_fused(const float* __restrict__ env,
                                                const float* __restrict__ c3,
                                                const float* __restrict__ sv,
                                                float* __restrict__ out) {
    __shared__ float c3s[1024], svs[1024], red[256];
    int t = threadIdx.x;
    int n0 = blockIdx.x * 64;            // region=(l,o,m)
    int l = n0 >> 12, o = (n0 >> 10) & 3, m = (n0 >> 6) & 15;
    const float* c3b = c3 + m * 65536 + o * 16384 + l * 1024;   // [a][sp]
    const float* eb  = env + (size_t)blockIdx.x * 4096;         // [a][b]
    for (int i = t; i < 1024; i += 256) { c3s[i] = c3b[i]; svs[i] = sv[i]; }
    __syncthreads();
    float s = 0;
    int b = t & 63, ag = t >> 6;
#pragma unroll
    for (int g = 0; g < 16; g++) {
        int a = ag * 16 + g;
        float e = eb[a * 64 + b];
        float w = 0;
#pragma unroll
        for (int sp = 0; sp < 16; sp++) w += c3s[a * 16 + sp] * svs[b * 16 + sp];
        s += e * w;
    }
    red[t] = s; __syncthreads();
    for (int off = 128; off; off >>= 1) { if (t < off) red[t] += red[t + off]; __syncthreads(); }
    if (t == 0) atomicAdd(out, red[0]);
}

// ---- G1 body: envS (pre-split u32, LDS-staged) x Sp1 -> t1 f16 panels ----
// bid in [0,2048): cc = bid>>10, rid = bid & 1023 = [l(16) o(4) m2(16)]
// smem: >= 8320 bytes
static __device__ __forceinline__ void g1_body(int bid, void* smem,
                                               const unsigned* __restrict__ envS,
                                               const unsigned short* __restrict__ Sp1,
                                               unsigned short* __restrict__ t1,
                                               float scale) {
    unsigned* Bt = (unsigned*)smem;
    const int tid = threadIdx.x, lane = tid & 63, wave = tid >> 6;
    const int quad = lane >> 4, lr = lane & 15;
    const int cc = bid >> 10, rid = bid & 1023;
    const int l = rid >> 6, o = (rid >> 4) & 3, m2 = rid & 15;

    f32x4 acc[4][4];
#pragma unroll
    for (int i = 0; i < 4; i++)
#pragma unroll
        for (int j = 0; j < 4; j++)
#pragma unroll
            for (int r = 0; r < 4; r++) acc[i][j][r] = 0.0f;

    const unsigned* Bv = envS + (size_t)rid * 4096;
    const unsigned short* Sp1c = Sp1 + (size_t)cc * 32768;
    uint4 ur[2];
    auto load_tile = [&](int k0) {
        const uint4* src = (const uint4*)(Bv + k0 * 2048);
        ur[0] = src[tid];
        ur[1] = src[256 + tid];
    };
    auto store_tile = [&]() {
#pragma unroll
        for (int v = 0; v < 2; v++) {
            int e = v * 256 + tid;
            unsigned* p = &Bt[(e >> 4) * 65 + (e & 15) * 4];
            p[0] = ur[v].x; p[1] = ur[v].y; p[2] = ur[v].z; p[3] = ur[v].w;
        }
    };

    bf16x8 ahb[2][4], alb[2][4];
    auto loadA = [&](int k0, int buf) {
#pragma unroll
        for (int mt = 0; mt < 4; mt++) {
            int gmt = wave * 4 + mt;
            const unsigned short* ap = Sp1c + ((size_t)(k0 * 16 + gmt) * 2) * 512 + lane * 8;
            ahb[buf][mt] = *(const bf16x8*)ap;
            alb[buf][mt] = *(const bf16x8*)(ap + 512);
        }
    };

    load_tile(0);
    loadA(0, 0);
    store_tile();
#pragma unroll
    for (int k0 = 0; k0 < 2; k0++) {
        __syncthreads();
        if (k0 + 1 < 2) { load_tile(k0 + 1); loadA(k0 + 1, 1); }
#pragma unroll
        for (int nt = 0; nt < 4; nt++) {
            int nl = nt * 16 + lr;
            bf16x8 bh, bl;
#pragma unroll
            for (int j = 0; j < 8; j++) {
                unsigned u = Bt[(quad * 8 + j) * 65 + nl];
                bh[j] = (short)(u & 0xffffu);
                bl[j] = (short)(u >> 16);
            }
#pragma unroll
            for (int mt = 0; mt < 4; mt++) {
                acc[mt][nt] = __builtin_amdgcn_mfma_f32_16x16x32_bf16(ahb[k0][mt], bh, acc[mt][nt], 0, 0, 0);
                acc[mt][nt] = __builtin_amdgcn_mfma_f32_16x16x32_bf16(ahb[k0][mt], bl, acc[mt][nt], 0, 0, 0);
                acc[mt][nt] = __builtin_amdgcn_mfma_f32_16x16x32_bf16(alb[k0][mt], bh, acc[mt][nt], 0, 0, 0);
            }
        }
        __syncthreads();
        if (k0 + 1 < 2) store_tile();
    }

#pragma unroll
    for (int nt = 0; nt < 4; nt++) {
        int b = nt * 16 + lr;
#pragma unroll
        for (int r = 0; r < 4; r++) {
            int a4 = quad * 4 + r;
            us4 w;
#pragma unroll
            for (int mt = 0; mt < 4; mt++) w[mt] = f2h_bits(acc[mt][nt][r] * scale);
            size_t addr = (size_t)cc * 16777216 +
                          (size_t)(o * 256 + m2 * 16 + a4) * 16384 +
                          (size_t)(l * 2 + (wave >> 1)) * 512 + b * 8 + (wave & 1) * 4;
            *(us4*)(t1 + addr) = w;
        }
    }
}

__global__ __launch_bounds__(256) void gemm_g1(const unsigned* __restrict__ envS,
                                               const unsigned short* __restrict__ Sp1,
                                               unsigned short* __restrict__ t1,
                                               float scale) {
    __shared__ unsigned Bt[32 * 65];
    g1_body(blockIdx.x, Bt, envS, Sp1, t1, scale);
}

// ---- G2 body: B panel LDS-staged via global_load_lds; A depth-2 prefetch -
// bid in [0,2048): cc = bid>>10, rid = [o(4) m2(16) a4(16)]
// smem: >= 32768 bytes, 16-aligned
static __device__ __forceinline__ void g2_body(int bid, void* smem,
                                               const unsigned short* __restrict__ Bp,
                                               const unsigned short* __restrict__ Ap,
                                               unsigned short* __restrict__ Co) {
    unsigned short* Bs = (unsigned short*)smem;
    const int tid = threadIdx.x, lane = tid & 63, wave = tid >> 6;
    const int quad = lane >> 4, lr = lane & 15;
    const int cc = bid >> 10, rid = bid & 1023;
    const int o = rid >> 8, m2 = (rid >> 4) & 15, a4 = rid & 15;
    const unsigned short* pb = Bp + (size_t)bid * 16384;
    unsigned short* Cb = Co + (size_t)cc * 16777216;

#pragma unroll
    for (int i = 0; i < 8; i++)
        gl_lds16(pb + i * 2048 + tid * 8, Bs + i * 2048 + wave * 512);

    f32x4 acc[4][4];
#pragma unroll
    for (int i = 0; i < 4; i++)
#pragma unroll
        for (int j = 0; j < 4; j++)
#pragma unroll
            for (int r = 0; r < 4; r++) acc[i][j][r] = 0.0f;

    f16x8 ah[3][4];
    auto loadA = [&](int k0, int buf) {
#pragma unroll
        for (int mt = 0; mt < 4; mt++) {
            int gmt = wave * 4 + mt;
            ah[buf][mt] = *(const f16x8*)(Ap + ((size_t)(k0 * 16 + gmt) * 2) * 512 + lane * 8);
        }
    };
    loadA(0, 0);
    loadA(1, 1);

    asm volatile("s_waitcnt vmcnt(0)" ::: "memory");
    __syncthreads();

#pragma unroll
    for (int k0 = 0; k0 < 8; k0++) {
        if (k0 + 2 < 8) loadA(k0 + 2, (k0 + 2) % 3);
        f16x8 bfr[4];
#pragma unroll
        for (int nt = 0; nt < 4; nt++)
            bfr[nt] = *(const f16x8*)(Bs + (k0 * 4 + quad) * 512 + (nt * 16 + lr) * 8);
#pragma unroll
        for (int nt = 0; nt < 4; nt++)
#pragma unroll
            for (int mt = 0; mt < 4; mt++)
                acc[mt][nt] = __builtin_amdgcn_mfma_f32_16x16x32_f16(
                    ah[k0 % 3][mt], bfr[nt], acc[mt][nt], 0, 0, 0);
    }

#pragma unroll
    for (int nt = 0; nt < 4; nt++) {
        int b = nt * 16 + lr;
#pragma unroll
        for (int r = 0; r < 4; r++) {
            int L = quad * 4 + r;
            us4 w;
#pragma unroll
            for (int mt = 0; mt < 4; mt++) w[mt] = f2h_bits(acc[mt][nt][r]);
            size_t addr = (size_t)(L * 256 + m2 * 16 + a4) * 4096 +
                          (size_t)(o * 2 + (wave >> 1)) * 512 + b * 8 + (wave & 1) * 4;
            *(us4*)(Cb + addr) = w;
        }
    }
}

__global__ __launch_bounds__(256) void gemm_g2(const unsigned short* __restrict__ Bp,
                                               const unsigned short* __restrict__ Ap,
                                               unsigned short* __restrict__ Co) {
    __shared__ __align__(16) unsigned short Bs[16384];
    g2_body(blockIdx.x, Bs, Bp, Ap, Co);
}

// ---- G45 body: fused G3+G4+G5 --------------------------------------------
// bid in [0,2048): cc = bid>>10; rid = g*32 + O2*8 + low, panel=(L,a4)=g*8+low
// smem: >= 32768 bytes (SL 17408 ALIASES Bs 32768 -- Bs dead after phase A;
// a __syncthreads() separates phase A reads from phase B slab writes).
static __device__ __forceinline__ void g45_body(int bid, void* smem,
                                                const unsigned short* __restrict__ T2,
                                                const unsigned short* __restrict__ Op3q,
                                                const unsigned short* __restrict__ Ap4,
                                                const unsigned short* __restrict__ Sp5,
                                                float* __restrict__ env,
                                                unsigned* __restrict__ envSo,
                                                int A0, float inv, int wf32) {
    unsigned short* Bs = (unsigned short*)smem;              // 32768 B
    unsigned* SL = (unsigned*)smem;                          // aliases Bs
    const int tid = threadIdx.x, lane = tid & 63, wave = tid >> 6;
    const int quad = lane >> 4, lr = lane & 15;
    const int cc = bid >> 10, rid = bid & 1023;
    const int low = rid & 7, O2 = (rid >> 3) & 3, g = rid >> 5;
    const int panel = g * 8 + low;           // = L*16 + a4
    const int L = panel >> 4, a4 = panel & 15;
    const unsigned short* T2c = T2 + (size_t)cc * 16777216;
    const int b8 = (wave * 16 + lr) * 8;   // b*8, b = wave*16+lr (g3 layout)

    // phase-A A-panel prefetch rides alongside the prologue
    f16x8 ah[3][4];
    auto loadA = [&](int k0, int buf) {
#pragma unroll
        for (int mt = 0; mt < 4; mt++) {
            int gmt = wave * 4 + mt;
            ah[buf][mt] = *(const f16x8*)(Ap4 + ((size_t)(k0 * 16 + gmt) * 2) * 512 + lane * 8);
        }
    };
    loadA(0, 0);
    loadA(1, 1);

    // ---- fused G3 prologue: build Bs = Op3[O2] x T2[(L,m2,a4)] -----------
    {
        f16x8 oh0 = *(const f16x8*)(Op3q + (size_t)(O2 * 2) * 512 + lane * 8);
        f16x8 oh1 = *(const f16x8*)(Op3q + (size_t)((4 + O2) * 2) * 512 + lane * 8);
        f16x8 tb[5][2];    // depth-4 ring
        auto loadT2 = [&](int m2, int buf) {
            const unsigned short* pp = T2c + (size_t)(L * 256 + m2 * 16 + a4) * 4096;
            tb[buf][0] = *(const f16x8*)(pp + (quad << 9) + b8);
            tb[buf][1] = *(const f16x8*)(pp + ((4 + quad) << 9) + b8);
        };
        loadT2(0, 0); loadT2(1, 1); loadT2(2, 2); loadT2(3, 3);
#pragma unroll
        for (int m2 = 0; m2 < 16; m2++) {
            if (m2 + 4 < 16) loadT2(m2 + 4, (m2 + 4) % 5);
            f32x4 a3;
            a3[0] = a3[1] = a3[2] = a3[3] = 0.0f;
            a3 = __builtin_amdgcn_mfma_f32_16x16x32_f16(oh0, tb[m2 % 5][0], a3, 0, 0, 0);
            a3 = __builtin_amdgcn_mfma_f32_16x16x32_f16(oh1, tb[m2 % 5][1], a3, 0, 0, 0);
            us4 w;
#pragma unroll
            for (int r = 0; r < 4; r++) w[r] = f2h_bits(a3[r]);
            *(us4*)(Bs + (m2 * 2 + (quad >> 1)) * 512 + b8 + (quad & 1) * 4) = w;
        }
    }
    __syncthreads();

    f32x4 acc[4][4];
#pragma unroll
    for (int i = 0; i < 4; i++)
#pragma unroll
        for (int j = 0; j < 4; j++)
#pragma unroll
            for (int r = 0; r < 4; r++) acc[i][j][r] = 0.0f;

#pragma unroll
    for (int k0 = 0; k0 < 8; k0++) {
        if (k0 + 2 < 8) loadA(k0 + 2, (k0 + 2) % 3);
        f16x8 bfr[4];
#pragma unroll
        for (int nt = 0; nt < 4; nt++)
            bfr[nt] = *(const f16x8*)(Bs + (k0 * 4 + quad) * 512 + (nt * 16 + lr) * 8);
#pragma unroll
        for (int nt = 0; nt < 4; nt++)
#pragma unroll
            for (int mt = 0; mt < 4; mt++)
                acc[mt][nt] = __builtin_amdgcn_mfma_f32_16x16x32_f16(
                    ah[k0 % 3][mt], bfr[nt], acc[mt][nt], 0, 0, 0);
    }

    // all waves done reading Bs before slab writes alias it
    __syncthreads();

    // phase B: per-wave k-quarter (s = 4*wave..4*wave+3), barrier-free.
    unsigned* myslab = SL + wave * (16 * 68);
    f32x4 acc5[4];
#pragma unroll
    for (int nt = 0; nt < 4; nt++)
#pragma unroll
        for (int r = 0; r < 4; r++) acc5[nt][r] = 0.0f;

    // Sp5 depth-1 pipeline: step = mtp*2+h, buffers by step parity.
    bf16x8 s5h[2][4], s5l[2][4];
    auto loadS5 = [&](int step, int buf) {
        int kg = (wave * 4 + (step >> 1)) * 2 + (step & 1);
#pragma unroll
        for (int nt = 0; nt < 4; nt++) {
            const unsigned short* bp = Sp5 + ((size_t)(kg * 4 + nt) * 2) * 512 + lane * 8;
            s5h[buf][nt] = *(const bf16x8*)bp;
            s5l[buf][nt] = *(const bf16x8*)(bp + 512);
        }
    };
    loadS5(0, 0);

#pragma unroll
    for (int mtp = 0; mtp < 4; mtp++) {
        // deposit own slab [M2=16][b=64 pad 68] via HW cvt_pk pairs
#pragma unroll
        for (int nt = 0; nt < 4; nt++) {
            unsigned o0, o1, o2, o3;
            split2_pair(acc[mtp][nt][0], acc[mtp][nt][1], o0, o1);
            split2_pair(acc[mtp][nt][2], acc[mtp][nt][3], o2, o3);
            myslab[(quad * 4 + 0) * 68 + nt * 16 + lr] = o0;
            myslab[(quad * 4 + 1) * 68 + nt * 16 + lr] = o1;
            myslab[(quad * 4 + 2) * 68 + nt * 16 + lr] = o2;
            myslab[(quad * 4 + 3) * 68 + nt * 16 + lr] = o3;
        }
        // same-wave cross-lane LDS dependency: drain LDS pipe (vmcnt loads
        // from loadS5 stay in flight - lgkmcnt does not wait on them)
        asm volatile("s_waitcnt lgkmcnt(0)" ::: "memory");
#pragma unroll
        for (int h = 0; h < 2; h++) {
            const int step = mtp * 2 + h;
            const unsigned* sp = &myslab[lr * 68 + h * 32 + quad * 8];
            uint4 u0 = *(const uint4*)sp;
            uint4 u1 = *(const uint4*)(sp + 4);
            bf16x8 th, tl;
            th[0] = (short)(u0.x & 0xffff); tl[0] = (short)(u0.x >> 16);
            th[1] = (short)(u0.y & 0xffff); tl[1] = (short)(u0.y >> 16);
            th[2] = (short)(u0.z & 0xffff); tl[2] = (short)(u0.z >> 16);
            th[3] = (short)(u0.w & 0xffff); tl[3] = (short)(u0.w >> 16);
            th[4] = (short)(u1.x & 0xffff); tl[4] = (short)(u1.x >> 16);
            th[5] = (short)(u1.y & 0xffff); tl[5] = (short)(u1.y >> 16);
            th[6] = (short)(u1.z & 0xffff); tl[6] = (short)(u1.z >> 16);
            th[7] = (short)(u1.w & 0xffff); tl[7] = (short)(u1.w >> 16);
            if (step + 1 < 8) loadS5(step + 1, (step + 1) & 1);
#pragma unroll
            for (int nt = 0; nt < 4; nt++) {
                acc5[nt] = __builtin_amdgcn_mfma_f32_16x16x32_bf16(th, s5h[step & 1][nt], acc5[nt], 0, 0, 0);
                acc5[nt] = __builtin_amdgcn_mfma_f32_16x16x32_bf16(th, s5l[step & 1][nt], acc5[nt], 0, 0, 0);
                acc5[nt] = __builtin_amdgcn_mfma_f32_16x16x32_bf16(tl, s5h[step & 1][nt], acc5[nt], 0, 0, 0);
            }
        }
    }

    // cross-wave reduce: one barrier, float view of SL
    __syncthreads();
    float* red = (float*)SL;
#pragma unroll
    for (int nt = 0; nt < 4; nt++)
#pragma unroll
        for (int r = 0; r < 4; r++)
            red[wave * 1088 + (quad * 4 + r) * 68 + nt * 16 + lr] = acc5[nt][r];
    __syncthreads();
    float wv[4];
#pragma unroll
    for (int r = 0; r < 4; r++) {
        int M2 = quad * 4 + r, Bc = wave * 16 + lr;
        float v = red[M2 * 68 + Bc] + red[1088 + M2 * 68 + Bc] +
                  red[2176 + M2 * 68 + Bc] + red[3264 + M2 * 68 + Bc];
        wv[r] = v * inv;
    }
    unsigned s0p, s1p, s2p, s3p;
    split2_pair(wv[0], wv[1], s0p, s1p);
    split2_pair(wv[2], wv[3], s2p, s3p);
    unsigned sp4[4] = {s0p, s1p, s2p, s3p};
#pragma unroll
    for (int r = 0; r < 4; r++) {
        int M2 = quad * 4 + r, Bc = wave * 16 + lr;
        size_t idx = (size_t)(L * 64 + O2 * 16 + M2) * 4096 + (A0 + cc * 16 + a4) * 64 + Bc;
        envSo[idx] = sp4[r];
        if (wf32) env[idx] = wv[r];
    }
}

__global__ __launch_bounds__(256) void gemm_g45(const unsigned short* __restrict__ T2,
                                                const unsigned short* __restrict__ Op3q,
                                                const unsigned short* __restrict__ Ap4,
                                                const unsigned short* __restrict__ Sp5,
                                                float* __restrict__ env,
                                                unsigned* __restrict__ envSo,
                                                int A0, float inv, int wf32) {
    __shared__ __align__(16) unsigned char smem[32768];
    g45_body(blockIdx.x, smem, T2, Op3q, Ap4, Sp5, env, envSo, A0, inv, wf32);
}

// ---- fused heterogeneous A: g2(p0) || g1(p1), 8-granular interleave ------
// grp = bid>>3 alternates branches; sub = (grp>>1)*8 + (bid&7).
// Both branches span all 8 XCDs; pool = max(32KB, 8.3KB) = 32KB.
__global__ __launch_bounds__(256) void fused_g2_g1(
        const unsigned short* __restrict__ Bp,     // g2: T1p0
        const unsigned short* __restrict__ Ap,     // g2: Ap2
        unsigned short* __restrict__ Co,           // g2: T2p0
        const unsigned* __restrict__ envS,         // g1: einS
        const unsigned short* __restrict__ Sp1b,   // g1: Sp1 p1 slice
        unsigned short* __restrict__ t1,           // g1: T1p1
        float scale) {
    __shared__ __align__(16) unsigned char smem[32768];
    const int grp = blockIdx.x >> 3;
    const int sub = (grp >> 1) * 8 + (blockIdx.x & 7);
    if (grp & 1)
        g1_body(sub, smem, envS, Sp1b, t1, scale);
    else
        g2_body(sub, smem, Bp, Ap, Co);
}

extern "C" void kernel_launch(void* const* d_in, const int* in_sizes, int n_in,
                              void* d_out, int out_size, void* d_ws, size_t ws_size,
                              hipStream_t stream) {
    const float* state = (const float*)d_in[0];   // [8,64,16,64]
    const float* layer = (const float*)d_in[1];   // [1,8,16,16,16,16]
    const float* oper  = (const float*)d_in[2];   // [8,4,16,16,4]
    float* out = (float*)d_out;

    // F 64MiB (T2p0/SCR) | P 128MiB (T1p0|T2p1 + T1p1) | envS0 | envB | envS1
    const size_t need = 16777216ull * 4 + 33554432ull * 4 + 3ull * 4194304ull * 4 +
                        (4ull * 1048576ull + 65536ull) * 2ull + 4096ull;
    if (ws_size < need) {
        write_diag_kernel<<<1, 64, 0, stream>>>(out, (float)ws_size);
        return;
    }
    float* F    = (float*)d_ws;                          // SCR fp32 / T2p0 u16
    unsigned* P = (unsigned*)(F + 16777216);             // T1p0(|T2p1) + T1p1
    unsigned* envS0 = (unsigned*)(P + 33554432);
    float* envB = (float*)(envS0 + 4194304);
    unsigned* envS1 = (unsigned*)(envB + 4194304);
    unsigned short* Ap2 = (unsigned short*)(envS1 + 4194304);
    unsigned short* Ap4 = Ap2 + 1048576;
    unsigned short* Sp1 = Ap4 + 1048576;
    unsigned short* Sp5 = Sp1 + 1048576;
    unsigned short* Op3 = Sp5 + 1048576;
    float* sv = (float*)(Op3 + 65536);
    float* SCR = F;
    unsigned short* T1p0 = (unsigned short*)P;           // aliased by T2p1
    unsigned short* T1p1 = T1p0 + 33554432;
    unsigned short* T2p0 = (unsigned short*)F;
    unsigned short* T2p1 = T1p0;                         // T1p0 dead by then

    prep_apack<<<256, 256, 0, stream>>>(layer, Ap2, Ap4);
    prep_spack1<<<256, 256, 0, stream>>>(state, Sp1);
    prep_spack5<<<256, 256, 0, stream>>>(state, Sp5);
    prep_opack3<<<16, 256, 0, stream>>>(oper, Op3);
    prep_sv<<<4, 256, 0, stream>>>(state, sv);

    // site 0 -> envB (exact fp32), then one split into envS1
    s0_g2<<<64, 256, 0, stream>>>(state, layer, SCR);
    s0_g3<<<256, 256, 0, stream>>>(SCR, oper, SCR + 16384);
    s0_g4<<<4096, 256, 0, stream>>>(SCR + 16384, layer, SCR + 81920);
    s0_env<<<16384, 256, 0, stream>>>(SCR + 81920, state, envB);
    env_split_k<<<4096, 256, 0, stream>>>(envB, envS1);

    for (int q = 1; q < 7; q++) {
        unsigned* einS  = (q & 1) ? envS1 : envS0;
        unsigned* eoutS = (q & 1) ? envS0 : envS1;
        float scl = (float)(1u << (16 + 2 * q));   // exact power of 2
        float inv = 1.0f / scl;
        int wf32 = (q == 6) ? 1 : 0;
        // g1(p0): einS -> T1p0
        gemm_g1<<<2048, 256, 0, stream>>>(
            einS, Sp1 + (size_t)(q * 4 + 0) * 32768, T1p0, scl);
        // fused A: g2(p0): T1p0 -> T2p0  ||  g1(p1): einS -> T1p1
        fused_g2_g1<<<4096, 256, 0, stream>>>(
            T1p0, Ap2 + (size_t)q * 131072, T2p0,
            einS, Sp1 + (size_t)(q * 4 + 2) * 32768, T1p1, scl);
        // g45(p0): T2p0 -> eoutS[A 0..31]
        gemm_g45<<<2048, 256, 0, stream>>>(
            T2p0, Op3 + (size_t)q * 8192, Ap4 + (size_t)q * 131072,
            Sp5 + (size_t)q * 131072, envB, eoutS, 0, inv, wf32);
        // g2(p1): T1p1 -> T2p1 (aliases T1p0, dead after fused A)
        gemm_g2<<<2048, 256, 0, stream>>>(
            T1p1, Ap2 + (size_t)q * 131072, T2p1);
        // g45(p1): T2p1 -> eoutS[A 32..63]
        gemm_g45<<<2048, 256, 0, stream>>>(
            T2p1, Op3 + (size_t)q * 8192, Ap4 + (size_t)q * 131072,
            Sp5 + (size_t)q * 131072, envB, eoutS, 32, inv, wf32);
    }

    // site 7: out = <env7 (in envB), w>
    s7_c1<<<64, 256, 0, stream>>>(state, layer, SCR);
    s7_c2<<<256, 256, 0, stream>>>(SCR, oper, SCR + 16384);
    s7_c3<<<4096, 256, 0, stream>>>(SCR + 16384, layer, SCR + 81920);
    zero_out<<<1, 64, 0, stream>>>(out);
    s7_fused<<<1024, 256, 0, stream>>>(envB, SCR + 81920, sv, out);
}